// Round 1
// baseline (595.180 us; speedup 1.0000x reference)
//
#include <hip/hip_runtime.h>

typedef _Float16 f16x8 __attribute__((ext_vector_type(8)));
typedef _Float16 f16x4 __attribute__((ext_vector_type(4)));
typedef float    f32x4 __attribute__((ext_vector_type(4)));
typedef int      i32x4 __attribute__((ext_vector_type(4)));

// ---------------- elementwise cast fp32 -> fp16 ----------------
__global__ __launch_bounds__(256) void cast_f32_f16(const float* __restrict__ src,
                                                    _Float16* __restrict__ dst, int n4) {
  int i = blockIdx.x * 256 + threadIdx.x;
  if (i < n4) {
    f32x4 v = *(const f32x4*)(src + (size_t)i * 4);
    f16x4 o;
    o[0] = (_Float16)v[0]; o[1] = (_Float16)v[1];
    o[2] = (_Float16)v[2]; o[3] = (_Float16)v[3];
    *(f16x4*)(dst + (size_t)i * 4) = o;
  }
}

// ---------------- transpose + cast: src (K x N fp32, row-major) -> dst[(rowOff+n)*ldDst + k] fp16
__global__ __launch_bounds__(256) void wtrans_kernel(const float* __restrict__ src,
                                                     _Float16* __restrict__ dst,
                                                     int N, int K, int rowOff, int ldDst) {
  const int n0 = blockIdx.x * 64, k0 = blockIdx.y * 64;
  __shared__ float tile[64][65];
#pragma unroll
  for (int i = 0; i < 16; ++i) {
    int id = i * 256 + threadIdx.x;
    int kk = id >> 6, nn = id & 63;
    tile[kk][nn] = src[(size_t)(k0 + kk) * N + n0 + nn];
  }
  __syncthreads();
#pragma unroll
  for (int i = 0; i < 16; ++i) {
    int id = i * 256 + threadIdx.x;
    int nn = id >> 6, kk = id & 63;
    dst[(size_t)(rowOff + n0 + nn) * ldDst + k0 + kk] = (_Float16)tile[kk][nn];
  }
}

// ---------------- pack bq|bk|bv into one fp32[3072] ----------------
__global__ __launch_bounds__(256) void biaspack_kernel(const float* __restrict__ bq,
                                                       const float* __restrict__ bk,
                                                       const float* __restrict__ bv,
                                                       float* __restrict__ out) {
  int i = blockIdx.x * 256 + threadIdx.x;
  if (i < 3072) out[i] = (i < 2048) ? bq[i] : (i < 2560 ? bk[i - 2048] : bv[i - 2560]);
}

// ---------------- GEMM: C(MxN) = A(MxK) * B^T(NxK) + bias, fp16 in, fp32 acc ----------------
// 128x128 tile, BK=64, 4 waves (2x2), each wave 64x64 = 4x4 fragments of 16x16x32 MFMA.
template <bool F16OUT>
__global__ __launch_bounds__(256) void gemm_nt(const _Float16* __restrict__ A,
                                               const _Float16* __restrict__ B,
                                               const float* __restrict__ bias,
                                               void* __restrict__ Cv,
                                               int M, int N, int K) {
  __shared__ __align__(16) _Float16 As[128][64];
  __shared__ __align__(16) _Float16 Bs[128][64];
  const int tid = threadIdx.x;
  const int lane = tid & 63, wave = tid >> 6;
  const int wr = wave >> 1, wc = wave & 1;
  const int r = lane & 15, g = lane >> 4;
  const int rb = blockIdx.y * 128, cb = blockIdx.x * 128;

  f32x4 acc[4][4] = {};

  for (int kt = 0; kt < K; kt += 64) {
    __syncthreads();
#pragma unroll
    for (int p = 0; p < 4; ++p) {
      int id = p * 256 + tid;
      int row = id >> 3, c = id & 7;
      int cs = c ^ (row & 7);  // XOR swizzle: 128B rows would otherwise be bank-aliased
      *(i32x4*)(&As[row][cs * 8]) = *(const i32x4*)(A + (size_t)(rb + row) * K + kt + c * 8);
      *(i32x4*)(&Bs[row][cs * 8]) = *(const i32x4*)(B + (size_t)(cb + row) * K + kt + c * 8);
    }
    __syncthreads();
#pragma unroll
    for (int kk = 0; kk < 2; ++kk) {
      f16x8 af[4], bf[4];
#pragma unroll
      for (int m = 0; m < 4; ++m) {
        int row = wr * 64 + m * 16 + r;
        af[m] = *(const f16x8*)(&As[row][((kk * 4 + g) ^ (row & 7)) * 8]);
      }
#pragma unroll
      for (int n = 0; n < 4; ++n) {
        int row = wc * 64 + n * 16 + r;
        bf[n] = *(const f16x8*)(&Bs[row][((kk * 4 + g) ^ (row & 7)) * 8]);
      }
#pragma unroll
      for (int m = 0; m < 4; ++m)
#pragma unroll
        for (int n = 0; n < 4; ++n)
          acc[m][n] = __builtin_amdgcn_mfma_f32_16x16x32_f16(af[m], bf[n], acc[m][n], 0, 0, 0);
    }
  }

  float bvals[4];
#pragma unroll
  for (int n = 0; n < 4; ++n) bvals[n] = bias[cb + wc * 64 + n * 16 + r];
#pragma unroll
  for (int m = 0; m < 4; ++m) {
#pragma unroll
    for (int n = 0; n < 4; ++n) {
#pragma unroll
      for (int j = 0; j < 4; ++j) {
        // D layout: row=(lane>>4)*4+j, col=lane&15  [guide m89]
        int row = rb + wr * 64 + m * 16 + g * 4 + j;
        int col = cb + wc * 64 + n * 16 + r;
        float v = acc[m][n][j] + bvals[n];
        if (F16OUT)
          ((_Float16*)Cv)[(size_t)row * N + col] = (_Float16)v;
        else
          ((float*)Cv)[(size_t)row * N + col] = v;
      }
    }
  }
}

// ---------------- RoPE in-place on QKV (cols [0,2048) = Q 16 heads, [2048,2560) = K 4 heads)
__global__ __launch_bounds__(256) void rope_kernel(_Float16* __restrict__ QKV) {
  const int tok = blockIdx.x;
  const int t = tok & 2047;  // position within sequence (tok = b*T + t)
  __shared__ float cs[64], sn[64];
  if (threadIdx.x < 64) {
    int j = threadIdx.x;
    // inv_freq = base^(-2j/128) = exp2(-2j/128 * log2(1e6))
    float freq = exp2f((float)(-2 * j) * (19.931568569324174f / 128.0f));
    float ang = (float)t * freq;
    cs[j] = cosf(ang);
    sn[j] = sinf(ang);
  }
  __syncthreads();
  _Float16* base = QKV + (size_t)tok * 3072;
  for (int idx = threadIdx.x; idx < 1280; idx += 256) {  // 20 heads * 64 freq pairs
    int head = idx >> 6, j = idx & 63;
    int cb = (head < 16) ? head * 128 : 2048 + (head - 16) * 128;
    _Float16* p = base + cb;
    float x1 = (float)p[j], x2 = (float)p[j + 64];
    float c = cs[j], s = sn[j];
    p[j]      = (_Float16)(x1 * c - x2 * s);
    p[j + 64] = (_Float16)(x2 * c + x1 * s);
  }
}

// ---------------- transpose V slabs: QKV cols [2560,3072) -> Vt[(b*4+kvh)][d][t]
__global__ __launch_bounds__(256) void vtrans_kernel(const _Float16* __restrict__ QKV,
                                                     _Float16* __restrict__ Vt) {
  const int bk = blockIdx.z;  // b*4+kvh
  const int t0 = blockIdx.x * 64, d0 = blockIdx.y * 64;
  const int b = bk >> 2, kvh = bk & 3;
  __shared__ _Float16 tile[64][65];
  const _Float16* src = QKV + (size_t)b * 2048 * 3072 + 2560 + kvh * 128;  // [t][d], ld 3072
#pragma unroll
  for (int i = 0; i < 16; ++i) {
    int id = i * 256 + threadIdx.x;
    int tt = id >> 6, dd = id & 63;
    tile[tt][dd] = src[(size_t)(t0 + tt) * 3072 + d0 + dd];
  }
  __syncthreads();
  _Float16* dst = Vt + (size_t)bk * 128 * 2048;  // [d][t], ld 2048
#pragma unroll
  for (int i = 0; i < 16; ++i) {
    int id = i * 256 + threadIdx.x;
    int dd = id >> 6, tt = id & 63;
    dst[(size_t)(d0 + dd) * 2048 + t0 + tt] = tile[tt][dd];
  }
}

// ---------------- causal GQA flash attention ----------------
// grid (T/64, H=16, B=2), 256 threads = 4 waves; each wave owns 16 q-rows independently.
__global__ __launch_bounds__(256) void attn_kernel(const _Float16* __restrict__ QKV,
                                                   const _Float16* __restrict__ Vt,
                                                   _Float16* __restrict__ O) {
  const int qt = blockIdx.x, h = blockIdx.y, b = blockIdx.z;
  const int tid = threadIdx.x;
  const int wave = tid >> 6, lane = tid & 63;
  const int r = lane & 15, g = lane >> 4;
  const int q0 = qt * 64 + wave * 16;
  const int kvh = h >> 2;
  const _Float16* Qb = QKV + (size_t)b * 2048 * 3072 + h * 128;
  const _Float16* Kb = QKV + (size_t)b * 2048 * 3072 + 2048 + kvh * 128;
  const _Float16* Vb = Vt + (size_t)(b * 4 + kvh) * 128 * 2048;
  __shared__ __align__(16) _Float16 Plds[4][16][32];

  // Q fragments (pre-scaled by 1/sqrt(128)), kept in registers for the whole loop
  f16x8 qf[4];
  {
    const _Float16* qrow = Qb + (size_t)(q0 + r) * 3072 + g * 8;
#pragma unroll
    for (int c = 0; c < 4; ++c) {
      f16x8 v = *(const f16x8*)(qrow + c * 32);
#pragma unroll
      for (int i = 0; i < 8; ++i) v[i] = (_Float16)((float)v[i] * 0.08838834764831845f);
      qf[c] = v;
    }
  }

  f32x4 oacc[8] = {};
  float mrun[4] = {-1e30f, -1e30f, -1e30f, -1e30f};
  float lrun[4] = {0.f, 0.f, 0.f, 0.f};

  const int kend = q0 + 16;  // keys < kend
  for (int kb = 0; kb < kend; kb += 32) {
    // S = Q K^T (16 rows x 32 keys), fp32
    f32x4 s[2] = {};
#pragma unroll
    for (int n = 0; n < 2; ++n) {
      const _Float16* krow = Kb + (size_t)(kb + n * 16 + r) * 3072 + g * 8;
#pragma unroll
      for (int c = 0; c < 4; ++c) {
        f16x8 kf = *(const f16x8*)(krow + c * 32);
        s[n] = __builtin_amdgcn_mfma_f32_16x16x32_f16(qf[c], kf, s[n], 0, 0, 0);
      }
    }
    // causal mask: col > row -> -1e30
#pragma unroll
    for (int n = 0; n < 2; ++n) {
      int col = kb + n * 16 + r;
#pragma unroll
      for (int j = 0; j < 4; ++j)
        if (col > q0 + g * 4 + j) s[n][j] = -1e30f;
    }
    // online softmax; row j lives on 16 lanes of the same g-group
    float mt[4], mnew[4], alpha[4], rs[4], p0[4], p1[4];
#pragma unroll
    for (int j = 0; j < 4; ++j) mt[j] = fmaxf(s[0][j], s[1][j]);
#pragma unroll
    for (int off = 8; off >= 1; off >>= 1)
#pragma unroll
      for (int j = 0; j < 4; ++j) mt[j] = fmaxf(mt[j], __shfl_xor(mt[j], off));
#pragma unroll
    for (int j = 0; j < 4; ++j) {
      mnew[j] = fmaxf(mrun[j], mt[j]);
      alpha[j] = __expf(mrun[j] - mnew[j]);
      p0[j] = __expf(s[0][j] - mnew[j]);
      p1[j] = __expf(s[1][j] - mnew[j]);
      rs[j] = p0[j] + p1[j];
    }
#pragma unroll
    for (int off = 8; off >= 1; off >>= 1)
#pragma unroll
      for (int j = 0; j < 4; ++j) rs[j] += __shfl_xor(rs[j], off);
#pragma unroll
    for (int j = 0; j < 4; ++j) {
      lrun[j] = lrun[j] * alpha[j] + rs[j];
      mrun[j] = mnew[j];
    }
#pragma unroll
    for (int f = 0; f < 8; ++f)
#pragma unroll
      for (int j = 0; j < 4; ++j) oacc[f][j] *= alpha[j];

    // P (D-layout) -> LDS -> re-read in A-fragment layout. Wave-internal only:
    // compiler fence + lgkmcnt(0) instead of __syncthreads (divergent trip counts).
    asm volatile("" ::: "memory");
#pragma unroll
    for (int j = 0; j < 4; ++j) {
      Plds[wave][g * 4 + j][r]      = (_Float16)p0[j];
      Plds[wave][g * 4 + j][16 + r] = (_Float16)p1[j];
    }
    asm volatile("s_waitcnt lgkmcnt(0)" ::: "memory");
    __builtin_amdgcn_sched_barrier(0);
    f16x8 pa = *(const f16x8*)(&Plds[wave][r][g * 8]);

    // O += P * V   (V read d-major from Vt: B[k][n] = Vt[n][k], contiguous k)
#pragma unroll
    for (int f = 0; f < 8; ++f) {
      f16x8 vf = *(const f16x8*)(Vb + (size_t)(f * 16 + r) * 2048 + kb + g * 8);
      oacc[f] = __builtin_amdgcn_mfma_f32_16x16x32_f16(pa, vf, oacc[f], 0, 0, 0);
    }
  }

  // epilogue: O[row][h*128+d] = oacc / l
#pragma unroll
  for (int j = 0; j < 4; ++j) {
    float inv = 1.0f / lrun[j];
    _Float16* orow = O + (size_t)(b * 2048 + q0 + g * 4 + j) * 2048 + h * 128;
#pragma unroll
    for (int f = 0; f < 8; ++f) orow[f * 16 + r] = (_Float16)(oacc[f][j] * inv);
  }
}

// ---------------- launch ----------------
extern "C" void kernel_launch(void* const* d_in, const int* in_sizes, int n_in,
                              void* d_out, int out_size, void* d_ws, size_t ws_size,
                              hipStream_t stream) {
  const float* x  = (const float*)d_in[0];
  const float* Wq = (const float*)d_in[1];
  const float* bq = (const float*)d_in[2];
  const float* Wk = (const float*)d_in[3];
  const float* bk = (const float*)d_in[4];
  const float* Wv = (const float*)d_in[5];
  const float* bv = (const float*)d_in[6];
  const float* Wo = (const float*)d_in[7];
  const float* bo = (const float*)d_in[8];
  float* out = (float*)d_out;

  char* ws = (char*)d_ws;
  constexpr size_t QKV_OFF  = 0;                         // 4096*3072*2 = 25165824
  constexpr size_t VT_OFF   = 25165824;                  // 8*128*2048*2 = 4194304
  constexpr size_t ATTN_OFF = VT_OFF + 4194304;          // 4096*2048*2 = 16777216
  constexpr size_t WT_OFF   = ATTN_OFF + 16777216;       // 3072*2048*2 = 12582912
  constexpr size_t BIAS_OFF = WT_OFF + 12582912;         // 3072*4
  _Float16* QKV  = (_Float16*)(ws + QKV_OFF);
  _Float16* Vt   = (_Float16*)(ws + VT_OFF);
  _Float16* attn = (_Float16*)(ws + ATTN_OFF);
  _Float16* WT   = (_Float16*)(ws + WT_OFF);
  float*    bqkv = (float*)(ws + BIAS_OFF);
  // xb (fp16 x, 16.8 MB) lives in d_out (33.5 MB, fp32) — dead before final GEMM writes it
  _Float16* xb = (_Float16*)d_out;

  // 1. cast x to fp16
  cast_f32_f16<<<8192, 256, 0, stream>>>(x, xb, (2 * 2048 * 2048) / 4);
  // 2. W^T fp16: rows [0,2048)=Wq, [2048,2560)=Wk, [2560,3072)=Wv   (ld = 2048)
  wtrans_kernel<<<dim3(32, 32), 256, 0, stream>>>(Wq, WT, 2048, 2048, 0, 2048);
  wtrans_kernel<<<dim3(8, 32), 256, 0, stream>>>(Wk, WT, 512, 2048, 2048, 2048);
  wtrans_kernel<<<dim3(8, 32), 256, 0, stream>>>(Wv, WT, 512, 2048, 2560, 2048);
  biaspack_kernel<<<12, 256, 0, stream>>>(bq, bk, bv, bqkv);
  // 3. QKV = x @ Wqkv + b  (M=4096, N=3072, K=2048), fp16 out
  gemm_nt<true><<<dim3(3072 / 128, 4096 / 128), 256, 0, stream>>>(xb, WT, bqkv, QKV, 4096, 3072, 2048);
  // 4. Wo^T into WT (reuse; QKV GEMM already consumed it)
  wtrans_kernel<<<dim3(32, 32), 256, 0, stream>>>(Wo, WT, 2048, 2048, 0, 2048);
  // 5. RoPE on Q and K
  rope_kernel<<<4096, 256, 0, stream>>>(QKV);
  // 6. V^T slabs for the PV MFMA
  vtrans_kernel<<<dim3(32, 2, 8), 256, 0, stream>>>(QKV, Vt);
  // 7. attention
  attn_kernel<<<dim3(32, 16, 2), 256, 0, stream>>>(QKV, Vt, attn);
  // 8. out = attn @ Wo + bo (fp32 out)
  gemm_nt<false><<<dim3(2048 / 128, 4096 / 128), 256, 0, stream>>>(attn, WT, bo, out, 4096, 2048, 2048);
}

// Round 2
// 267.665 us; speedup vs baseline: 2.2236x; 2.2236x over previous
//
#include <hip/hip_runtime.h>

typedef _Float16 f16x8 __attribute__((ext_vector_type(8)));
typedef _Float16 f16x4 __attribute__((ext_vector_type(4)));
typedef float    f32x4 __attribute__((ext_vector_type(4)));

__device__ __forceinline__ void gload16(const void* g, void* l) {
  __builtin_amdgcn_global_load_lds((const __attribute__((address_space(1))) void*)g,
                                   (__attribute__((address_space(3))) void*)l, 16, 0, 0);
}

// ---------------- elementwise cast fp32 -> fp16 ----------------
__global__ __launch_bounds__(256) void cast_f32_f16(const float* __restrict__ src,
                                                    _Float16* __restrict__ dst, int n4) {
  int i = blockIdx.x * 256 + threadIdx.x;
  if (i < n4) {
    f32x4 v = *(const f32x4*)(src + (size_t)i * 4);
    f16x4 o;
    o[0] = (_Float16)v[0]; o[1] = (_Float16)v[1];
    o[2] = (_Float16)v[2]; o[3] = (_Float16)v[3];
    *(f16x4*)(dst + (size_t)i * 4) = o;
  }
}

// ---------------- transpose + cast: src (K x N fp32) -> dst[(rowOff+n)*ldDst + k] fp16
__global__ __launch_bounds__(256) void wtrans_kernel(const float* __restrict__ src,
                                                     _Float16* __restrict__ dst,
                                                     int N, int K, int rowOff, int ldDst) {
  const int n0 = blockIdx.x * 64, k0 = blockIdx.y * 64;
  __shared__ float tile[64][65];
#pragma unroll
  for (int i = 0; i < 16; ++i) {
    int id = i * 256 + threadIdx.x;
    int kk = id >> 6, nn = id & 63;
    tile[kk][nn] = src[(size_t)(k0 + kk) * N + n0 + nn];
  }
  __syncthreads();
#pragma unroll
  for (int i = 0; i < 16; ++i) {
    int id = i * 256 + threadIdx.x;
    int nn = id >> 6, kk = id & 63;
    dst[(size_t)(rowOff + n0 + nn) * ldDst + k0 + kk] = (_Float16)tile[kk][nn];
  }
}

// ---------------- pack bq|bk|bv ----------------
__global__ __launch_bounds__(256) void biaspack_kernel(const float* __restrict__ bq,
                                                       const float* __restrict__ bk,
                                                       const float* __restrict__ bv,
                                                       float* __restrict__ out) {
  int i = blockIdx.x * 256 + threadIdx.x;
  if (i < 3072) out[i] = (i < 2048) ? bq[i] : (i < 2560 ? bk[i - 2048] : bv[i - 2560]);
}

// ---------------- GEMM: C = A(MxK) * B^T(NxK) + bias ----------------
// 128x128 tile, BK=64, 4 waves. global_load_lds staging, pre-swizzled source:
// LDS[row][cc] holds global chunk cc^(row&7); reader reads chunk u^(row&7).
template <bool F16OUT>
__global__ __launch_bounds__(256) void gemm_nt(const _Float16* __restrict__ A,
                                               const _Float16* __restrict__ B,
                                               const float* __restrict__ bias,
                                               void* __restrict__ Cv,
                                               int M, int N, int K) {
  __shared__ __align__(16) _Float16 As[128][64];
  __shared__ __align__(16) _Float16 Bs[128][64];
  const int tid = threadIdx.x;
  const int lane = tid & 63, wave = tid >> 6;
  const int wr = wave >> 1, wc = wave & 1;
  const int r = lane & 15, g = lane >> 4;
  const int rb = blockIdx.y * 128, cb = blockIdx.x * 128;

  // staging: issue p covers rows p*32..p*32+31; lane-chunk cc = tid&7, row = p*32+(tid>>3)
  const int swz = ((tid & 7) ^ ((tid >> 3) & 7)) * 8;
  const _Float16* aSrc = A + (size_t)(rb + (tid >> 3)) * K + swz;
  const _Float16* bSrc = B + (size_t)(cb + (tid >> 3)) * K + swz;

  f32x4 acc[4][4] = {};

  for (int kt = 0; kt < K; kt += 64) {
    __syncthreads();
#pragma unroll
    for (int p = 0; p < 4; ++p) {
      gload16(aSrc + (size_t)(p * 32) * K + kt, (_Float16*)As + (p * 256 + wave * 64) * 8);
      gload16(bSrc + (size_t)(p * 32) * K + kt, (_Float16*)Bs + (p * 256 + wave * 64) * 8);
    }
    __syncthreads();
#pragma unroll
    for (int kk = 0; kk < 2; ++kk) {
      f16x8 af[4], bf[4];
#pragma unroll
      for (int m = 0; m < 4; ++m) {
        int row = wr * 64 + m * 16 + r;
        af[m] = *(const f16x8*)(&As[row][((kk * 4 + g) ^ (row & 7)) * 8]);
      }
#pragma unroll
      for (int n = 0; n < 4; ++n) {
        int row = wc * 64 + n * 16 + r;
        bf[n] = *(const f16x8*)(&Bs[row][((kk * 4 + g) ^ (row & 7)) * 8]);
      }
#pragma unroll
      for (int m = 0; m < 4; ++m)
#pragma unroll
        for (int n = 0; n < 4; ++n)
          acc[m][n] = __builtin_amdgcn_mfma_f32_16x16x32_f16(af[m], bf[n], acc[m][n], 0, 0, 0);
    }
  }

  float bvals[4];
#pragma unroll
  for (int n = 0; n < 4; ++n) bvals[n] = bias[cb + wc * 64 + n * 16 + r];
#pragma unroll
  for (int m = 0; m < 4; ++m) {
#pragma unroll
    for (int n = 0; n < 4; ++n) {
#pragma unroll
      for (int j = 0; j < 4; ++j) {
        int row = rb + wr * 64 + m * 16 + g * 4 + j;
        int col = cb + wc * 64 + n * 16 + r;
        float v = acc[m][n][j] + bvals[n];
        if (F16OUT)
          ((_Float16*)Cv)[(size_t)row * N + col] = (_Float16)v;
        else
          ((float*)Cv)[(size_t)row * N + col] = v;
      }
    }
  }
}

// ---------------- RoPE in-place on QKV ----------------
__global__ __launch_bounds__(256) void rope_kernel(_Float16* __restrict__ QKV) {
  const int tok = blockIdx.x;
  const int t = tok & 2047;
  __shared__ float cs[64], sn[64];
  if (threadIdx.x < 64) {
    int j = threadIdx.x;
    float freq = exp2f((float)(-2 * j) * (19.931568569324174f / 128.0f));
    float ang = (float)t * freq;
    cs[j] = cosf(ang);
    sn[j] = sinf(ang);
  }
  __syncthreads();
  _Float16* base = QKV + (size_t)tok * 3072;
  for (int idx = threadIdx.x; idx < 1280; idx += 256) {
    int head = idx >> 6, j = idx & 63;
    int cb = (head < 16) ? head * 128 : 2048 + (head - 16) * 128;
    _Float16* p = base + cb;
    float x1 = (float)p[j], x2 = (float)p[j + 64];
    float c = cs[j], s = sn[j];
    p[j]      = (_Float16)(x1 * c - x2 * s);
    p[j + 64] = (_Float16)(x2 * c + x1 * s);
  }
}

// ---------------- transpose V slabs: QKV cols [2560,3072) -> Vt[(b*4+kvh)][d][t]
__global__ __launch_bounds__(256) void vtrans_kernel(const _Float16* __restrict__ QKV,
                                                     _Float16* __restrict__ Vt) {
  const int bk = blockIdx.z;
  const int t0 = blockIdx.x * 64, d0 = blockIdx.y * 64;
  const int b = bk >> 2, kvh = bk & 3;
  __shared__ _Float16 tile[64][65];
  const _Float16* src = QKV + (size_t)b * 2048 * 3072 + 2560 + kvh * 128;
#pragma unroll
  for (int i = 0; i < 16; ++i) {
    int id = i * 256 + threadIdx.x;
    int tt = id >> 6, dd = id & 63;
    tile[tt][dd] = src[(size_t)(t0 + tt) * 3072 + d0 + dd];
  }
  __syncthreads();
  _Float16* dst = Vt + (size_t)bk * 128 * 2048;
#pragma unroll
  for (int i = 0; i < 16; ++i) {
    int id = i * 256 + threadIdx.x;
    int dd = id >> 6, tt = id & 63;
    dst[(size_t)(d0 + dd) * 2048 + t0 + tt] = tile[tt][dd];
  }
}

// ---------------- causal GQA flash attention v2 ----------------
// grid (T/64, 16, 2), 256 thr = 4 waves. Block stages K[64][128]/V^T[128][64]
// in swizzled LDS (global_load_lds, pre-swizzled source). Swapped QK^T:
// mfma(K,Q) -> S^T, lane owns q-row = lane&15; softmax is in-lane + 2 shuffles.
__global__ __launch_bounds__(256) void attn_kernel(const _Float16* __restrict__ QKV,
                                                   const _Float16* __restrict__ Vt,
                                                   _Float16* __restrict__ O) {
  const int qt = blockIdx.x, h = blockIdx.y, b = blockIdx.z;
  const int tid = threadIdx.x;
  const int wave = tid >> 6, lane = tid & 63;
  const int r = lane & 15, g = lane >> 4;
  const int q0 = qt * 64 + wave * 16;  // this wave's first q-row
  const int kvh = h >> 2;
  const _Float16* Qb  = QKV + (size_t)b * 2048 * 3072 + h * 128;
  const _Float16* Kb  = QKV + (size_t)b * 2048 * 3072 + 2048 + kvh * 128;
  const _Float16* Vtg = Vt + (size_t)(b * 4 + kvh) * 128 * 2048;

  __shared__ __align__(16) _Float16 Klds[64][128];   // [k][d], 16 chunks/row, swz cc^(k&7)
  __shared__ __align__(16) _Float16 Vlds[128][64];   // [d][k],  8 chunks/row, swz cc^(d&7)
  __shared__ __align__(16) _Float16 Plds[4][16][64]; // per-wave P, 8 chunks/row, swz cc^(r&7)

  // staging source addresses (pre-swizzled so linear LDS dest + swizzled read match)
  const _Float16* kSrc = Kb  + (size_t)(tid >> 4) * 3072 + (((tid & 15) ^ ((tid >> 4) & 7)) * 8);
  const _Float16* vSrc = Vtg + (size_t)(tid >> 3) * 2048 + (((tid & 7) ^ ((tid >> 3) & 7)) * 8);

  // Q fragments, pre-scaled by 1/sqrt(128)
  f16x8 qf[4];
  {
    const _Float16* qrow = Qb + (size_t)(q0 + r) * 3072 + g * 8;
#pragma unroll
    for (int c = 0; c < 4; ++c) {
      f16x8 v = *(const f16x8*)(qrow + c * 32);
#pragma unroll
      for (int i = 0; i < 8; ++i) v[i] = (_Float16)((float)v[i] * 0.08838834764831845f);
      qf[c] = v;
    }
  }

  f32x4 oacc[8] = {};
  float mrun = -1e30f, lrun = 0.f;
  const int kend = qt * 64 + 64;
  const int qlim = q0 + 16;

  for (int kb = 0; kb < kend; kb += 64) {
#pragma unroll
    for (int p = 0; p < 4; ++p) {
      gload16(kSrc + (size_t)(kb + p * 16) * 3072, (_Float16*)Klds + (p * 256 + wave * 64) * 8);
      gload16(vSrc + (size_t)(p * 32) * 2048 + kb, (_Float16*)Vlds + (p * 256 + wave * 64) * 8);
    }
    __syncthreads();  // drains vmcnt: staged tiles visible
    if (kb < qlim) {
      // S^T[64k][16q] = K_tile @ Q^T : lane holds S[k=n*16+g*4+j][q=r]
      f32x4 sT[4] = {};
#pragma unroll
      for (int c = 0; c < 4; ++c) {
#pragma unroll
        for (int n = 0; n < 4; ++n) {
          f16x8 kf = *(const f16x8*)(&Klds[n * 16 + r][(((c * 4 + g) ^ (r & 7)) * 8)]);
          sT[n] = __builtin_amdgcn_mfma_f32_16x16x32_f16(kf, qf[c], sT[n], 0, 0, 0);
        }
      }
      // causal mask + row max (in-lane 16 + cross-g 2 shuffles)
      float mt = -1e30f;
#pragma unroll
      for (int n = 0; n < 4; ++n)
#pragma unroll
        for (int j = 0; j < 4; ++j) {
          int kg = kb + n * 16 + g * 4 + j;
          if (kg > q0 + r) sT[n][j] = -1e30f;
          mt = fmaxf(mt, sT[n][j]);
        }
      mt = fmaxf(mt, __shfl_xor(mt, 16));
      mt = fmaxf(mt, __shfl_xor(mt, 32));
      float mnew = fmaxf(mrun, mt);
      float alpha = __expf(mrun - mnew);
      float p[4][4];
      float rs = 0.f;
#pragma unroll
      for (int n = 0; n < 4; ++n)
#pragma unroll
        for (int j = 0; j < 4; ++j) {
          p[n][j] = __expf(sT[n][j] - mnew);
          rs += p[n][j];
        }
      rs += __shfl_xor(rs, 16);
      rs += __shfl_xor(rs, 32);
      lrun = lrun * alpha + rs;
      mrun = mnew;
      // rescale O: oacc[dt][jj] belongs to q=g*4+jj -> fetch that row's alpha
      float al[4];
#pragma unroll
      for (int jj = 0; jj < 4; ++jj) al[jj] = __shfl(alpha, g * 4 + jj);
#pragma unroll
      for (int dt = 0; dt < 8; ++dt)
#pragma unroll
        for (int jj = 0; jj < 4; ++jj) oacc[dt][jj] *= al[jj];
      // P -> LDS (16B-chunk swizzle), wave-internal round trip
      asm volatile("" ::: "memory");
#pragma unroll
      for (int n = 0; n < 4; ++n) {
        f16x4 p4;
#pragma unroll
        for (int j = 0; j < 4; ++j) p4[j] = (_Float16)p[n][j];
        int c16s = (2 * n + (g >> 1)) ^ (r & 7);
        *(f16x4*)(&Plds[wave][r][c16s * 8 + (g & 1) * 4]) = p4;
      }
      asm volatile("s_waitcnt lgkmcnt(0)" ::: "memory");
      __builtin_amdgcn_sched_barrier(0);
      f16x8 pa0 = *(const f16x8*)(&Plds[wave][r][((g) ^ (r & 7)) * 8]);
      f16x8 pa1 = *(const f16x8*)(&Plds[wave][r][((4 + g) ^ (r & 7)) * 8]);
      // O += P @ V : B-frag from Vlds rows (V^T), output col=r is d, row=g*4+jj is q
#pragma unroll
      for (int dt = 0; dt < 8; ++dt) {
        f16x8 vf0 = *(const f16x8*)(&Vlds[dt * 16 + r][((g) ^ (r & 7)) * 8]);
        oacc[dt] = __builtin_amdgcn_mfma_f32_16x16x32_f16(pa0, vf0, oacc[dt], 0, 0, 0);
        f16x8 vf1 = *(const f16x8*)(&Vlds[dt * 16 + r][((4 + g) ^ (r & 7)) * 8]);
        oacc[dt] = __builtin_amdgcn_mfma_f32_16x16x32_f16(pa1, vf1, oacc[dt], 0, 0, 0);
      }
    }
    __syncthreads();  // protect K/V LDS before next stage
  }

  // epilogue
  float linv = 1.0f / lrun;
  float li[4];
#pragma unroll
  for (int jj = 0; jj < 4; ++jj) li[jj] = __shfl(linv, g * 4 + jj);
#pragma unroll
  for (int dt = 0; dt < 8; ++dt)
#pragma unroll
    for (int jj = 0; jj < 4; ++jj)
      O[(size_t)(b * 2048 + q0 + g * 4 + jj) * 2048 + h * 128 + dt * 16 + r] =
          (_Float16)(oacc[dt][jj] * li[jj]);
}

// ---------------- launch ----------------
extern "C" void kernel_launch(void* const* d_in, const int* in_sizes, int n_in,
                              void* d_out, int out_size, void* d_ws, size_t ws_size,
                              hipStream_t stream) {
  const float* x  = (const float*)d_in[0];
  const float* Wq = (const float*)d_in[1];
  const float* bq = (const float*)d_in[2];
  const float* Wk = (const float*)d_in[3];
  const float* bk = (const float*)d_in[4];
  const float* Wv = (const float*)d_in[5];
  const float* bv = (const float*)d_in[6];
  const float* Wo = (const float*)d_in[7];
  const float* bo = (const float*)d_in[8];
  float* out = (float*)d_out;

  char* ws = (char*)d_ws;
  constexpr size_t QKV_OFF  = 0;                       // 25165824
  constexpr size_t VT_OFF   = 25165824;                // 4194304
  constexpr size_t ATTN_OFF = VT_OFF + 4194304;        // 16777216
  constexpr size_t WT_OFF   = ATTN_OFF + 16777216;     // 12582912
  constexpr size_t BIAS_OFF = WT_OFF + 12582912;
  _Float16* QKV  = (_Float16*)(ws + QKV_OFF);
  _Float16* Vt   = (_Float16*)(ws + VT_OFF);
  _Float16* attn = (_Float16*)(ws + ATTN_OFF);
  _Float16* WT   = (_Float16*)(ws + WT_OFF);
  float*    bqkv = (float*)(ws + BIAS_OFF);
  _Float16* xb = (_Float16*)d_out;  // dead before final GEMM writes d_out

  cast_f32_f16<<<8192, 256, 0, stream>>>(x, xb, (2 * 2048 * 2048) / 4);
  wtrans_kernel<<<dim3(32, 32), 256, 0, stream>>>(Wq, WT, 2048, 2048, 0, 2048);
  wtrans_kernel<<<dim3(8, 32), 256, 0, stream>>>(Wk, WT, 512, 2048, 2048, 2048);
  wtrans_kernel<<<dim3(8, 32), 256, 0, stream>>>(Wv, WT, 512, 2048, 2560, 2048);
  biaspack_kernel<<<12, 256, 0, stream>>>(bq, bk, bv, bqkv);
  gemm_nt<true><<<dim3(3072 / 128, 4096 / 128), 256, 0, stream>>>(xb, WT, bqkv, QKV, 4096, 3072, 2048);
  wtrans_kernel<<<dim3(32, 32), 256, 0, stream>>>(Wo, WT, 2048, 2048, 0, 2048);
  rope_kernel<<<4096, 256, 0, stream>>>(QKV);
  vtrans_kernel<<<dim3(32, 2, 8), 256, 0, stream>>>(QKV, Vt);
  attn_kernel<<<dim3(32, 16, 2), 256, 0, stream>>>(QKV, Vt, attn);
  gemm_nt<false><<<dim3(2048 / 128, 4096 / 128), 256, 0, stream>>>(attn, WT, bo, out, 4096, 2048, 2048);
}

// Round 3
// 225.615 us; speedup vs baseline: 2.6380x; 1.1864x over previous
//
#include <hip/hip_runtime.h>

typedef _Float16 f16x8 __attribute__((ext_vector_type(8)));
typedef _Float16 f16x4 __attribute__((ext_vector_type(4)));
typedef float    f32x4 __attribute__((ext_vector_type(4)));

__device__ __forceinline__ void gload16(const void* g, void* l) {
  __builtin_amdgcn_global_load_lds((const __attribute__((address_space(1))) void*)g,
                                   (__attribute__((address_space(3))) void*)l, 16, 0, 0);
}

// ---------------- elementwise cast fp32 -> fp16 ----------------
__global__ __launch_bounds__(256) void cast_f32_f16(const float* __restrict__ src,
                                                    _Float16* __restrict__ dst, int n4) {
  int i = blockIdx.x * 256 + threadIdx.x;
  if (i < n4) {
    f32x4 v = *(const f32x4*)(src + (size_t)i * 4);
    f16x4 o;
    o[0] = (_Float16)v[0]; o[1] = (_Float16)v[1];
    o[2] = (_Float16)v[2]; o[3] = (_Float16)v[3];
    *(f16x4*)(dst + (size_t)i * 4) = o;
  }
}

// ---------------- transpose + cast: src (K x N fp32) -> dst[(rowOff+n)*ldDst + k] fp16
__global__ __launch_bounds__(256) void wtrans_kernel(const float* __restrict__ src,
                                                     _Float16* __restrict__ dst,
                                                     int N, int K, int rowOff, int ldDst) {
  const int n0 = blockIdx.x * 64, k0 = blockIdx.y * 64;
  __shared__ float tile[64][65];
#pragma unroll
  for (int i = 0; i < 16; ++i) {
    int id = i * 256 + threadIdx.x;
    int kk = id >> 6, nn = id & 63;
    tile[kk][nn] = src[(size_t)(k0 + kk) * N + n0 + nn];
  }
  __syncthreads();
#pragma unroll
  for (int i = 0; i < 16; ++i) {
    int id = i * 256 + threadIdx.x;
    int nn = id >> 6, kk = id & 63;
    dst[(size_t)(rowOff + n0 + nn) * ldDst + k0 + kk] = (_Float16)tile[kk][nn];
  }
}

// ---------------- pack bq|bk|bv ----------------
__global__ __launch_bounds__(256) void biaspack_kernel(const float* __restrict__ bq,
                                                       const float* __restrict__ bk,
                                                       const float* __restrict__ bv,
                                                       float* __restrict__ out) {
  int i = blockIdx.x * 256 + threadIdx.x;
  if (i < 3072) out[i] = (i < 2048) ? bq[i] : (i < 2560 ? bk[i - 2048] : bv[i - 2560]);
}

// ---------------- GEMM: C = A(MxK) * B^T(NxK) + bias ----------------
template <bool F16OUT>
__global__ __launch_bounds__(256) void gemm_nt(const _Float16* __restrict__ A,
                                               const _Float16* __restrict__ B,
                                               const float* __restrict__ bias,
                                               void* __restrict__ Cv,
                                               int M, int N, int K) {
  __shared__ __align__(16) _Float16 As[128][64];
  __shared__ __align__(16) _Float16 Bs[128][64];
  const int tid = threadIdx.x;
  const int lane = tid & 63, wave = tid >> 6;
  const int wr = wave >> 1, wc = wave & 1;
  const int r = lane & 15, g = lane >> 4;
  const int rb = blockIdx.y * 128, cb = blockIdx.x * 128;

  const int swz = ((tid & 7) ^ ((tid >> 3) & 7)) * 8;
  const _Float16* aSrc = A + (size_t)(rb + (tid >> 3)) * K + swz;
  const _Float16* bSrc = B + (size_t)(cb + (tid >> 3)) * K + swz;

  f32x4 acc[4][4] = {};

  for (int kt = 0; kt < K; kt += 64) {
    __syncthreads();
#pragma unroll
    for (int p = 0; p < 4; ++p) {
      gload16(aSrc + (size_t)(p * 32) * K + kt, (_Float16*)As + (p * 256 + wave * 64) * 8);
      gload16(bSrc + (size_t)(p * 32) * K + kt, (_Float16*)Bs + (p * 256 + wave * 64) * 8);
    }
    __syncthreads();
#pragma unroll
    for (int kk = 0; kk < 2; ++kk) {
      f16x8 af[4], bf[4];
#pragma unroll
      for (int m = 0; m < 4; ++m) {
        int row = wr * 64 + m * 16 + r;
        af[m] = *(const f16x8*)(&As[row][((kk * 4 + g) ^ (row & 7)) * 8]);
      }
#pragma unroll
      for (int n = 0; n < 4; ++n) {
        int row = wc * 64 + n * 16 + r;
        bf[n] = *(const f16x8*)(&Bs[row][((kk * 4 + g) ^ (row & 7)) * 8]);
      }
#pragma unroll
      for (int m = 0; m < 4; ++m)
#pragma unroll
        for (int n = 0; n < 4; ++n)
          acc[m][n] = __builtin_amdgcn_mfma_f32_16x16x32_f16(af[m], bf[n], acc[m][n], 0, 0, 0);
    }
  }

  float bvals[4];
#pragma unroll
  for (int n = 0; n < 4; ++n) bvals[n] = bias[cb + wc * 64 + n * 16 + r];
#pragma unroll
  for (int m = 0; m < 4; ++m) {
#pragma unroll
    for (int n = 0; n < 4; ++n) {
#pragma unroll
      for (int j = 0; j < 4; ++j) {
        int row = rb + wr * 64 + m * 16 + g * 4 + j;
        int col = cb + wc * 64 + n * 16 + r;
        float v = acc[m][n][j] + bvals[n];
        if (F16OUT)
          ((_Float16*)Cv)[(size_t)row * N + col] = (_Float16)v;
        else
          ((float*)Cv)[(size_t)row * N + col] = v;
      }
    }
  }
}

// ---------------- RoPE in-place on QKV ----------------
__global__ __launch_bounds__(256) void rope_kernel(_Float16* __restrict__ QKV) {
  const int tok = blockIdx.x;
  const int t = tok & 2047;
  __shared__ float cs[64], sn[64];
  if (threadIdx.x < 64) {
    int j = threadIdx.x;
    float freq = exp2f((float)(-2 * j) * (19.931568569324174f / 128.0f));
    float ang = (float)t * freq;
    cs[j] = cosf(ang);
    sn[j] = sinf(ang);
  }
  __syncthreads();
  _Float16* base = QKV + (size_t)tok * 3072;
  for (int idx = threadIdx.x; idx < 1280; idx += 256) {
    int head = idx >> 6, j = idx & 63;
    int cb = (head < 16) ? head * 128 : 2048 + (head - 16) * 128;
    _Float16* p = base + cb;
    float x1 = (float)p[j], x2 = (float)p[j + 64];
    float c = cs[j], s = sn[j];
    p[j]      = (_Float16)(x1 * c - x2 * s);
    p[j + 64] = (_Float16)(x2 * c + x1 * s);
  }
}

// ---------------- transpose V slabs -> Vt[(b*4+kvh)][d][t] ----------------
__global__ __launch_bounds__(256) void vtrans_kernel(const _Float16* __restrict__ QKV,
                                                     _Float16* __restrict__ Vt) {
  const int bk = blockIdx.z;
  const int t0 = blockIdx.x * 64, d0 = blockIdx.y * 64;
  const int b = bk >> 2, kvh = bk & 3;
  __shared__ _Float16 tile[64][65];
  const _Float16* src = QKV + (size_t)b * 2048 * 3072 + 2560 + kvh * 128;
#pragma unroll
  for (int i = 0; i < 16; ++i) {
    int id = i * 256 + threadIdx.x;
    int tt = id >> 6, dd = id & 63;
    tile[tt][dd] = src[(size_t)(t0 + tt) * 3072 + d0 + dd];
  }
  __syncthreads();
  _Float16* dst = Vt + (size_t)bk * 128 * 2048;
#pragma unroll
  for (int i = 0; i < 16; ++i) {
    int id = i * 256 + threadIdx.x;
    int dd = id >> 6, tt = id & 63;
    dst[(size_t)(d0 + dd) * 2048 + t0 + tt] = tile[tt][dd];
  }
}

// ---------------- causal GQA flash attention v3 ----------------
// QBLK=128, 8 waves x 512 thr, grid 512 flat blocks with complementary qt
// pairing (block i: qt, block i+256: 15-qt) so each CU's 2 blocks sum to
// constant work under round-robin dispatch. exp2-domain softmax, defer-max,
// diagonal-only masking.
__global__ __launch_bounds__(512) void attn_kernel(const _Float16* __restrict__ QKV,
                                                   const _Float16* __restrict__ Vt,
                                                   _Float16* __restrict__ O) {
  const int bid = blockIdx.x;
  const int b = bid >> 8;
  const int ii = bid & 255;
  const int h = ii >> 4;
  const int qtr = ii & 15;
  const int qt = b ? 15 - qtr : qtr;
  const int tid = threadIdx.x;
  const int wave = tid >> 6, lane = tid & 63;
  const int r = lane & 15, g = lane >> 4;
  const int q0 = qt * 128 + wave * 16;
  const int kvh = h >> 2;
  const _Float16* Qb  = QKV + (size_t)b * 2048 * 3072 + h * 128;
  const _Float16* Kb  = QKV + (size_t)b * 2048 * 3072 + 2048 + kvh * 128;
  const _Float16* Vtg = Vt + (size_t)(b * 4 + kvh) * 128 * 2048;

  __shared__ __align__(16) _Float16 Klds[64][128];   // [k][d], swz chunk cc^(k&7)
  __shared__ __align__(16) _Float16 Vlds[128][64];   // [d][k], swz chunk cc^(d&7)
  __shared__ __align__(16) _Float16 Plds[8][16][64];

  // pre-swizzled staging sources (linear LDS dest + swizzled read, rule #21)
  const _Float16* kSrc = Kb  + (size_t)(tid >> 4) * 3072 + (((tid & 15) ^ ((tid >> 4) & 7)) * 8);
  const _Float16* vSrc = Vtg + (size_t)(tid >> 3) * 2048 + (((tid & 7) ^ ((tid >> 3) & 7)) * 8);

  // Q fragments, scale folded with log2e so softmax runs in exp2 domain
  f16x8 qf[4];
  {
    const float qsc = 0.08838834764831845f * 1.4426950408889634f;
    const _Float16* qrow = Qb + (size_t)(q0 + r) * 3072 + g * 8;
#pragma unroll
    for (int c = 0; c < 4; ++c) {
      f16x8 v = *(const f16x8*)(qrow + c * 32);
#pragma unroll
      for (int i = 0; i < 8; ++i) v[i] = (_Float16)((float)v[i] * qsc);
      qf[c] = v;
    }
  }

  f32x4 oacc[8] = {};
  float mrun = -1e30f, lrun = 0.f;
  const int kend = qt * 128 + 128;
  const int qlim = q0 + 16;

  for (int kb = 0; kb < kend; kb += 64) {
    // stage K[64][128] + V^T[128][64]: 2 issues each, 8 waves
    gload16(kSrc + (size_t)kb * 3072,        (_Float16*)Klds + (wave * 64) * 8);
    gload16(kSrc + (size_t)(kb + 32) * 3072, (_Float16*)Klds + (512 + wave * 64) * 8);
    gload16(vSrc + kb,                       (_Float16*)Vlds + (wave * 64) * 8);
    gload16(vSrc + (size_t)64 * 2048 + kb,   (_Float16*)Vlds + (512 + wave * 64) * 8);
    __syncthreads();  // drains vmcnt: tiles visible
    if (kb < qlim) {
      // S^T = K_tile @ Q^T : lane holds S[k=n*16+g*4+j][q=r]
      f32x4 sT[4] = {};
#pragma unroll
      for (int c = 0; c < 4; ++c) {
#pragma unroll
        for (int n = 0; n < 4; ++n) {
          f16x8 kf = *(const f16x8*)(&Klds[n * 16 + r][(((c * 4 + g) ^ (r & 7)) * 8)]);
          sT[n] = __builtin_amdgcn_mfma_f32_16x16x32_f16(kf, qf[c], sT[n], 0, 0, 0);
        }
      }
      // causal mask only on near-diagonal tiles (wave-uniform branch)
      if (kb + 63 > q0) {
#pragma unroll
        for (int n = 0; n < 4; ++n)
#pragma unroll
          for (int j = 0; j < 4; ++j) {
            int kg = kb + n * 16 + g * 4 + j;
            if (kg > q0 + r) sT[n][j] = -1e30f;
          }
      }
      float mt = -1e30f;
#pragma unroll
      for (int n = 0; n < 4; ++n)
#pragma unroll
        for (int j = 0; j < 4; ++j) mt = fmaxf(mt, sT[n][j]);
      mt = fmaxf(mt, __shfl_xor(mt, 16));
      mt = fmaxf(mt, __shfl_xor(mt, 32));
      // defer-max: rescale only when the running max actually grows
      if (__any(mt > mrun)) {
        float mnew = fmaxf(mrun, mt);
        float alpha = exp2f(mrun - mnew);
        lrun *= alpha;
        float al[4];
#pragma unroll
        for (int jj = 0; jj < 4; ++jj) al[jj] = __shfl(alpha, g * 4 + jj);
#pragma unroll
        for (int dt = 0; dt < 8; ++dt)
#pragma unroll
          for (int jj = 0; jj < 4; ++jj) oacc[dt][jj] *= al[jj];
        mrun = mnew;
      }
      float p[4][4];
      float rs = 0.f;
#pragma unroll
      for (int n = 0; n < 4; ++n)
#pragma unroll
        for (int j = 0; j < 4; ++j) {
          p[n][j] = exp2f(sT[n][j] - mrun);
          rs += p[n][j];
        }
      rs += __shfl_xor(rs, 16);
      rs += __shfl_xor(rs, 32);
      lrun += rs;
      // P -> LDS (16B-chunk swizzle), wave-internal round trip
      asm volatile("" ::: "memory");
#pragma unroll
      for (int n = 0; n < 4; ++n) {
        f16x4 p4;
#pragma unroll
        for (int j = 0; j < 4; ++j) p4[j] = (_Float16)p[n][j];
        int c16s = (2 * n + (g >> 1)) ^ (r & 7);
        *(f16x4*)(&Plds[wave][r][c16s * 8 + (g & 1) * 4]) = p4;
      }
      asm volatile("s_waitcnt lgkmcnt(0)" ::: "memory");
      __builtin_amdgcn_sched_barrier(0);
      f16x8 pa0 = *(const f16x8*)(&Plds[wave][r][((g) ^ (r & 7)) * 8]);
      f16x8 pa1 = *(const f16x8*)(&Plds[wave][r][((4 + g) ^ (r & 7)) * 8]);
#pragma unroll
      for (int dt = 0; dt < 8; ++dt) {
        f16x8 vf0 = *(const f16x8*)(&Vlds[dt * 16 + r][((g) ^ (r & 7)) * 8]);
        oacc[dt] = __builtin_amdgcn_mfma_f32_16x16x32_f16(pa0, vf0, oacc[dt], 0, 0, 0);
        f16x8 vf1 = *(const f16x8*)(&Vlds[dt * 16 + r][((4 + g) ^ (r & 7)) * 8]);
        oacc[dt] = __builtin_amdgcn_mfma_f32_16x16x32_f16(pa1, vf1, oacc[dt], 0, 0, 0);
      }
    }
    __syncthreads();  // protect K/V LDS before next stage
  }

  float linv = 1.0f / lrun;
  float li[4];
#pragma unroll
  for (int jj = 0; jj < 4; ++jj) li[jj] = __shfl(linv, g * 4 + jj);
#pragma unroll
  for (int dt = 0; dt < 8; ++dt)
#pragma unroll
    for (int jj = 0; jj < 4; ++jj)
      O[(size_t)(b * 2048 + q0 + g * 4 + jj) * 2048 + h * 128 + dt * 16 + r] =
          (_Float16)(oacc[dt][jj] * li[jj]);
}

// ---------------- launch ----------------
extern "C" void kernel_launch(void* const* d_in, const int* in_sizes, int n_in,
                              void* d_out, int out_size, void* d_ws, size_t ws_size,
                              hipStream_t stream) {
  const float* x  = (const float*)d_in[0];
  const float* Wq = (const float*)d_in[1];
  const float* bq = (const float*)d_in[2];
  const float* Wk = (const float*)d_in[3];
  const float* bk = (const float*)d_in[4];
  const float* Wv = (const float*)d_in[5];
  const float* bv = (const float*)d_in[6];
  const float* Wo = (const float*)d_in[7];
  const float* bo = (const float*)d_in[8];
  float* out = (float*)d_out;

  char* ws = (char*)d_ws;
  constexpr size_t QKV_OFF  = 0;                       // 25165824
  constexpr size_t VT_OFF   = 25165824;                // 4194304
  constexpr size_t ATTN_OFF = VT_OFF + 4194304;        // 16777216
  constexpr size_t WT_OFF   = ATTN_OFF + 16777216;     // 12582912
  constexpr size_t BIAS_OFF = WT_OFF + 12582912;
  _Float16* QKV  = (_Float16*)(ws + QKV_OFF);
  _Float16* Vt   = (_Float16*)(ws + VT_OFF);
  _Float16* attn = (_Float16*)(ws + ATTN_OFF);
  _Float16* WT   = (_Float16*)(ws + WT_OFF);
  float*    bqkv = (float*)(ws + BIAS_OFF);
  _Float16* xb = (_Float16*)d_out;  // dead before final GEMM writes d_out

  cast_f32_f16<<<8192, 256, 0, stream>>>(x, xb, (2 * 2048 * 2048) / 4);
  wtrans_kernel<<<dim3(32, 32), 256, 0, stream>>>(Wq, WT, 2048, 2048, 0, 2048);
  wtrans_kernel<<<dim3(8, 32), 256, 0, stream>>>(Wk, WT, 512, 2048, 2048, 2048);
  wtrans_kernel<<<dim3(8, 32), 256, 0, stream>>>(Wv, WT, 512, 2048, 2560, 2048);
  biaspack_kernel<<<12, 256, 0, stream>>>(bq, bk, bv, bqkv);
  gemm_nt<true><<<dim3(3072 / 128, 4096 / 128), 256, 0, stream>>>(xb, WT, bqkv, QKV, 4096, 3072, 2048);
  wtrans_kernel<<<dim3(32, 32), 256, 0, stream>>>(Wo, WT, 2048, 2048, 0, 2048);
  rope_kernel<<<4096, 256, 0, stream>>>(QKV);
  vtrans_kernel<<<dim3(32, 2, 8), 256, 0, stream>>>(QKV, Vt);
  attn_kernel<<<512, 512, 0, stream>>>(QKV, Vt, attn);
  gemm_nt<false><<<dim3(2048 / 128, 4096 / 128), 256, 0, stream>>>(attn, WT, bo, out, 4096, 2048, 2048);
}

// Round 4
// 216.603 us; speedup vs baseline: 2.7478x; 1.0416x over previous
//
#include <hip/hip_runtime.h>

typedef _Float16 f16x8 __attribute__((ext_vector_type(8)));
typedef _Float16 f16x4 __attribute__((ext_vector_type(4)));
typedef float    f32x4 __attribute__((ext_vector_type(4)));

__device__ __forceinline__ void gload16(const void* g, void* l) {
  __builtin_amdgcn_global_load_lds((const __attribute__((address_space(1))) void*)g,
                                   (__attribute__((address_space(3))) void*)l, 16, 0, 0);
}

// ---------------- elementwise cast fp32 -> fp16 ----------------
__global__ __launch_bounds__(256) void cast_f32_f16(const float* __restrict__ src,
                                                    _Float16* __restrict__ dst, int n4) {
  int i = blockIdx.x * 256 + threadIdx.x;
  if (i < n4) {
    f32x4 v = *(const f32x4*)(src + (size_t)i * 4);
    f16x4 o;
    o[0] = (_Float16)v[0]; o[1] = (_Float16)v[1];
    o[2] = (_Float16)v[2]; o[3] = (_Float16)v[3];
    *(f16x4*)(dst + (size_t)i * 4) = o;
  }
}

// ---------------- merged Wq|Wk|Wv transpose+cast -> WT rows [0,3072) ----------------
__global__ __launch_bounds__(256) void wqkvtrans_kernel(const float* __restrict__ Wq,
                                                        const float* __restrict__ Wk,
                                                        const float* __restrict__ Wv,
                                                        _Float16* __restrict__ dst) {
  const int n0 = blockIdx.x * 64, k0 = blockIdx.y * 64;
  const float* src; int N, nb;
  if (n0 < 2048)      { src = Wq; N = 2048; nb = n0; }
  else if (n0 < 2560) { src = Wk; N = 512;  nb = n0 - 2048; }
  else                { src = Wv; N = 512;  nb = n0 - 2560; }
  __shared__ float tile[64][65];
#pragma unroll
  for (int i = 0; i < 16; ++i) {
    int id = i * 256 + threadIdx.x;
    int kk = id >> 6, nn = id & 63;
    tile[kk][nn] = src[(size_t)(k0 + kk) * N + nb + nn];
  }
  __syncthreads();
#pragma unroll
  for (int i = 0; i < 16; ++i) {
    int id = i * 256 + threadIdx.x;
    int nn = id >> 6, kk = id & 63;
    dst[(size_t)(n0 + nn) * 2048 + k0 + kk] = (_Float16)tile[kk][nn];
  }
}

// ---------------- transpose + cast (single source, for Wo) ----------------
__global__ __launch_bounds__(256) void wtrans_kernel(const float* __restrict__ src,
                                                     _Float16* __restrict__ dst,
                                                     int N, int K, int rowOff, int ldDst) {
  const int n0 = blockIdx.x * 64, k0 = blockIdx.y * 64;
  __shared__ float tile[64][65];
#pragma unroll
  for (int i = 0; i < 16; ++i) {
    int id = i * 256 + threadIdx.x;
    int kk = id >> 6, nn = id & 63;
    tile[kk][nn] = src[(size_t)(k0 + kk) * N + n0 + nn];
  }
  __syncthreads();
#pragma unroll
  for (int i = 0; i < 16; ++i) {
    int id = i * 256 + threadIdx.x;
    int nn = id >> 6, kk = id & 63;
    dst[(size_t)(rowOff + n0 + nn) * ldDst + k0 + kk] = (_Float16)tile[kk][nn];
  }
}

// ---------------- pack bq|bk|bv ----------------
__global__ __launch_bounds__(256) void biaspack_kernel(const float* __restrict__ bq,
                                                       const float* __restrict__ bk,
                                                       const float* __restrict__ bv,
                                                       float* __restrict__ out) {
  int i = blockIdx.x * 256 + threadIdx.x;
  if (i < 3072) out[i] = (i < 2048) ? bq[i] : (i < 2560 ? bk[i - 2048] : bv[i - 2560]);
}

// ---------------- GEMM: C = A(MxK) * B^T(NxK) + bias ----------------
template <bool F16OUT>
__global__ __launch_bounds__(256) void gemm_nt(const _Float16* __restrict__ A,
                                               const _Float16* __restrict__ B,
                                               const float* __restrict__ bias,
                                               void* __restrict__ Cv,
                                               int M, int N, int K) {
  __shared__ __align__(16) _Float16 As[128][64];
  __shared__ __align__(16) _Float16 Bs[128][64];
  const int tid = threadIdx.x;
  const int lane = tid & 63, wave = tid >> 6;
  const int wr = wave >> 1, wc = wave & 1;
  const int r = lane & 15, g = lane >> 4;
  const int rb = blockIdx.y * 128, cb = blockIdx.x * 128;

  const int swz = ((tid & 7) ^ ((tid >> 3) & 7)) * 8;
  const _Float16* aSrc = A + (size_t)(rb + (tid >> 3)) * K + swz;
  const _Float16* bSrc = B + (size_t)(cb + (tid >> 3)) * K + swz;

  f32x4 acc[4][4] = {};

  for (int kt = 0; kt < K; kt += 64) {
    __syncthreads();
#pragma unroll
    for (int p = 0; p < 4; ++p) {
      gload16(aSrc + (size_t)(p * 32) * K + kt, (_Float16*)As + (p * 256 + wave * 64) * 8);
      gload16(bSrc + (size_t)(p * 32) * K + kt, (_Float16*)Bs + (p * 256 + wave * 64) * 8);
    }
    __syncthreads();
#pragma unroll
    for (int kk = 0; kk < 2; ++kk) {
      f16x8 af[4], bf[4];
#pragma unroll
      for (int m = 0; m < 4; ++m) {
        int row = wr * 64 + m * 16 + r;
        af[m] = *(const f16x8*)(&As[row][((kk * 4 + g) ^ (row & 7)) * 8]);
      }
#pragma unroll
      for (int n = 0; n < 4; ++n) {
        int row = wc * 64 + n * 16 + r;
        bf[n] = *(const f16x8*)(&Bs[row][((kk * 4 + g) ^ (row & 7)) * 8]);
      }
#pragma unroll
      for (int m = 0; m < 4; ++m)
#pragma unroll
        for (int n = 0; n < 4; ++n)
          acc[m][n] = __builtin_amdgcn_mfma_f32_16x16x32_f16(af[m], bf[n], acc[m][n], 0, 0, 0);
    }
  }

  float bvals[4];
#pragma unroll
  for (int n = 0; n < 4; ++n) bvals[n] = bias[cb + wc * 64 + n * 16 + r];
#pragma unroll
  for (int m = 0; m < 4; ++m) {
#pragma unroll
    for (int n = 0; n < 4; ++n) {
#pragma unroll
      for (int j = 0; j < 4; ++j) {
        int row = rb + wr * 64 + m * 16 + g * 4 + j;
        int col = cb + wc * 64 + n * 16 + r;
        float v = acc[m][n][j] + bvals[n];
        if (F16OUT)
          ((_Float16*)Cv)[(size_t)row * N + col] = (_Float16)v;
        else
          ((float*)Cv)[(size_t)row * N + col] = v;
      }
    }
  }
}

// ---------------- RoPE in-place on QKV (vectorized f16x8) ----------------
__global__ __launch_bounds__(256) void rope_kernel(_Float16* __restrict__ QKV) {
  const int tok = blockIdx.x;
  const int t = tok & 2047;
  __shared__ float cs[64], sn[64];
  if (threadIdx.x < 64) {
    int j = threadIdx.x;
    float freq = exp2f((float)(-2 * j) * (19.931568569324174f / 128.0f));
    float ang = (float)t * freq;
    cs[j] = cosf(ang);
    sn[j] = sinf(ang);
  }
  __syncthreads();
  _Float16* base = QKV + (size_t)tok * 3072;
  int idx = threadIdx.x;
  if (idx < 160) {  // 20 heads x 8 vec-groups
    int head = idx >> 3, j0 = (idx & 7) * 8;
    int cb = (head < 16) ? head * 128 : 2048 + (head - 16) * 128;
    _Float16* p = base + cb;
    f16x8 a = *(const f16x8*)(p + j0);
    f16x8 b2 = *(const f16x8*)(p + 64 + j0);
    f16x8 oa, ob;
#pragma unroll
    for (int e = 0; e < 8; ++e) {
      float c = cs[j0 + e], s = sn[j0 + e];
      float x1 = (float)a[e], x2 = (float)b2[e];
      oa[e] = (_Float16)(x1 * c - x2 * s);
      ob[e] = (_Float16)(x2 * c + x1 * s);
    }
    *(f16x8*)(p + j0) = oa;
    *(f16x8*)(p + 64 + j0) = ob;
  }
}

// ---------------- transpose V slabs -> Vt[(b*4+kvh)][d][t] ----------------
__global__ __launch_bounds__(256) void vtrans_kernel(const _Float16* __restrict__ QKV,
                                                     _Float16* __restrict__ Vt) {
  const int bk = blockIdx.z;
  const int t0 = blockIdx.x * 64, d0 = blockIdx.y * 64;
  const int b = bk >> 2, kvh = bk & 3;
  __shared__ _Float16 tile[64][65];
  const _Float16* src = QKV + (size_t)b * 2048 * 3072 + 2560 + kvh * 128;
#pragma unroll
  for (int i = 0; i < 16; ++i) {
    int id = i * 256 + threadIdx.x;
    int tt = id >> 6, dd = id & 63;
    tile[tt][dd] = src[(size_t)(t0 + tt) * 3072 + d0 + dd];
  }
  __syncthreads();
  _Float16* dst = Vt + (size_t)bk * 128 * 2048;
#pragma unroll
  for (int i = 0; i < 16; ++i) {
    int id = i * 256 + threadIdx.x;
    int dd = id >> 6, tt = id & 63;
    dst[(size_t)(d0 + dd) * 2048 + t0 + tt] = tile[tt][dd];
  }
}

// ---------------- causal GQA flash attention v4 ----------------
// QBLK=128, 8 waves, complementary qt pairing. Double-buffered K/V LDS with
// T3-minimum pipeline: stage tile t+1 before computing tile t; raw s_barrier
// + counted vmcnt(4) so prefetch loads stay in flight across the barrier.
__global__ __launch_bounds__(512) void attn_kernel(const _Float16* __restrict__ QKV,
                                                   const _Float16* __restrict__ Vt,
                                                   _Float16* __restrict__ O) {
  const int bid = blockIdx.x;
  const int b = bid >> 8;
  const int ii = bid & 255;
  const int h = ii >> 4;
  const int qtr = ii & 15;
  const int qt = b ? 15 - qtr : qtr;
  const int tid = threadIdx.x;
  const int wave = tid >> 6, lane = tid & 63;
  const int r = lane & 15, g = lane >> 4;
  const int q0 = qt * 128 + wave * 16;
  const int kvh = h >> 2;
  const _Float16* Qb  = QKV + (size_t)b * 2048 * 3072 + h * 128;
  const _Float16* Kb  = QKV + (size_t)b * 2048 * 3072 + 2048 + kvh * 128;
  const _Float16* Vtg = Vt + (size_t)(b * 4 + kvh) * 128 * 2048;

  __shared__ __align__(16) _Float16 Klds[2][64][128];   // swz chunk cc^(k&7)
  __shared__ __align__(16) _Float16 Vlds[2][128][64];   // swz chunk cc^(d&7)
  __shared__ __align__(16) _Float16 Plds[8][16][64];

  // pre-swizzled staging sources (linear LDS dest + swizzled read, rule #21)
  const _Float16* kSrc = Kb  + (size_t)(tid >> 4) * 3072 + (((tid & 15) ^ ((tid >> 4) & 7)) * 8);
  const _Float16* vSrc = Vtg + (size_t)(tid >> 3) * 2048 + (((tid & 7) ^ ((tid >> 3) & 7)) * 8);

  // Q fragments first (force-complete before staging so vmcnt counting is exact)
  f16x8 qf[4];
  {
    const float qsc = 0.08838834764831845f * 1.4426950408889634f;
    const _Float16* qrow = Qb + (size_t)(q0 + r) * 3072 + g * 8;
#pragma unroll
    for (int c = 0; c < 4; ++c) {
      f16x8 v = *(const f16x8*)(qrow + c * 32);
#pragma unroll
      for (int i = 0; i < 8; ++i) v[i] = (_Float16)((float)v[i] * qsc);
      qf[c] = v;
    }
  }
  asm volatile("s_waitcnt vmcnt(0)" ::: "memory");  // Q retired; outstanding = 0

  f32x4 oacc[8] = {};
  float mrun = -1e30f, lrun = 0.f;
  const int kend = qt * 128 + 128;
  const int qlim = q0 + 16;

  // prologue: stage tile 0 into buffer 0  (4 loads/thread in flight)
  {
    gload16(kSrc,                          &Klds[0][0][0] + (wave * 64) * 8);
    gload16(kSrc + (size_t)32 * 3072,      &Klds[0][0][0] + (512 + wave * 64) * 8);
    gload16(vSrc,                          &Vlds[0][0][0] + (wave * 64) * 8);
    gload16(vSrc + (size_t)64 * 2048,      &Vlds[0][0][0] + (512 + wave * 64) * 8);
  }

  int cur = 0;
  for (int kb = 0; kb < kend; kb += 64) {
    if (kb + 64 < kend) {  // prefetch next tile into the other buffer
      int nb = kb + 64, nxt = cur ^ 1;
      gload16(kSrc + (size_t)nb * 3072,        &Klds[nxt][0][0] + (wave * 64) * 8);
      gload16(kSrc + (size_t)(nb + 32) * 3072, &Klds[nxt][0][0] + (512 + wave * 64) * 8);
      gload16(vSrc + nb,                       &Vlds[nxt][0][0] + (wave * 64) * 8);
      gload16(vSrc + (size_t)64 * 2048 + nb,   &Vlds[nxt][0][0] + (512 + wave * 64) * 8);
      asm volatile("s_waitcnt vmcnt(4)" ::: "memory");  // current tile landed; next 4 in flight
    } else {
      asm volatile("s_waitcnt vmcnt(0)" ::: "memory");
    }
    __builtin_amdgcn_s_barrier();          // all waves' current-tile stages visible
    __builtin_amdgcn_sched_barrier(0);     // pin ds_reads below the barrier
    if (kb < qlim) {
      // S^T = K_tile @ Q^T : lane holds S[k=n*16+g*4+j][q=r]
      f32x4 sT[4] = {};
      __builtin_amdgcn_s_setprio(1);
#pragma unroll
      for (int c = 0; c < 4; ++c) {
#pragma unroll
        for (int n = 0; n < 4; ++n) {
          f16x8 kf = *(const f16x8*)(&Klds[cur][n * 16 + r][(((c * 4 + g) ^ (r & 7)) * 8)]);
          sT[n] = __builtin_amdgcn_mfma_f32_16x16x32_f16(kf, qf[c], sT[n], 0, 0, 0);
        }
      }
      __builtin_amdgcn_s_setprio(0);
      // causal mask only on near-diagonal tiles (wave-uniform branch)
      if (kb + 63 > q0) {
#pragma unroll
        for (int n = 0; n < 4; ++n)
#pragma unroll
          for (int j = 0; j < 4; ++j) {
            int kg = kb + n * 16 + g * 4 + j;
            if (kg > q0 + r) sT[n][j] = -1e30f;
          }
      }
      float mt = -1e30f;
#pragma unroll
      for (int n = 0; n < 4; ++n)
#pragma unroll
        for (int j = 0; j < 4; ++j) mt = fmaxf(mt, sT[n][j]);
      mt = fmaxf(mt, __shfl_xor(mt, 16));
      mt = fmaxf(mt, __shfl_xor(mt, 32));
      if (__any(mt > mrun)) {  // defer-max
        float mnew = fmaxf(mrun, mt);
        float alpha = exp2f(mrun - mnew);
        lrun *= alpha;
        float al[4];
#pragma unroll
        for (int jj = 0; jj < 4; ++jj) al[jj] = __shfl(alpha, g * 4 + jj);
#pragma unroll
        for (int dt = 0; dt < 8; ++dt)
#pragma unroll
          for (int jj = 0; jj < 4; ++jj) oacc[dt][jj] *= al[jj];
        mrun = mnew;
      }
      float p[4][4];
      float rs = 0.f;
#pragma unroll
      for (int n = 0; n < 4; ++n)
#pragma unroll
        for (int j = 0; j < 4; ++j) {
          p[n][j] = exp2f(sT[n][j] - mrun);
          rs += p[n][j];
        }
      rs += __shfl_xor(rs, 16);
      rs += __shfl_xor(rs, 32);
      lrun += rs;
      // P -> LDS (16B-chunk swizzle), wave-internal round trip
      asm volatile("" ::: "memory");
#pragma unroll
      for (int n = 0; n < 4; ++n) {
        f16x4 p4;
#pragma unroll
        for (int j = 0; j < 4; ++j) p4[j] = (_Float16)p[n][j];
        int c16s = (2 * n + (g >> 1)) ^ (r & 7);
        *(f16x4*)(&Plds[wave][r][c16s * 8 + (g & 1) * 4]) = p4;
      }
      asm volatile("s_waitcnt lgkmcnt(0)" ::: "memory");
      __builtin_amdgcn_sched_barrier(0);
      f16x8 pa0 = *(const f16x8*)(&Plds[wave][r][((g) ^ (r & 7)) * 8]);
      f16x8 pa1 = *(const f16x8*)(&Plds[wave][r][((4 + g) ^ (r & 7)) * 8]);
      __builtin_amdgcn_s_setprio(1);
#pragma unroll
      for (int dt = 0; dt < 8; ++dt) {
        f16x8 vf0 = *(const f16x8*)(&Vlds[cur][dt * 16 + r][((g) ^ (r & 7)) * 8]);
        oacc[dt] = __builtin_amdgcn_mfma_f32_16x16x32_f16(pa0, vf0, oacc[dt], 0, 0, 0);
        f16x8 vf1 = *(const f16x8*)(&Vlds[cur][dt * 16 + r][((4 + g) ^ (r & 7)) * 8]);
        oacc[dt] = __builtin_amdgcn_mfma_f32_16x16x32_f16(pa1, vf1, oacc[dt], 0, 0, 0);
      }
      __builtin_amdgcn_s_setprio(0);
    }
    __builtin_amdgcn_sched_barrier(0);     // pin compute above the release barrier
    __builtin_amdgcn_s_barrier();          // all waves done reading buf[cur]
    __builtin_amdgcn_sched_barrier(0);     // pin next stage below it
    cur ^= 1;
  }

  float linv = 1.0f / lrun;
  float li[4];
#pragma unroll
  for (int jj = 0; jj < 4; ++jj) li[jj] = __shfl(linv, g * 4 + jj);
#pragma unroll
  for (int dt = 0; dt < 8; ++dt)
#pragma unroll
    for (int jj = 0; jj < 4; ++jj)
      O[(size_t)(b * 2048 + q0 + g * 4 + jj) * 2048 + h * 128 + dt * 16 + r] =
          (_Float16)(oacc[dt][jj] * li[jj]);
}

// ---------------- launch ----------------
extern "C" void kernel_launch(void* const* d_in, const int* in_sizes, int n_in,
                              void* d_out, int out_size, void* d_ws, size_t ws_size,
                              hipStream_t stream) {
  const float* x  = (const float*)d_in[0];
  const float* Wq = (const float*)d_in[1];
  const float* bq = (const float*)d_in[2];
  const float* Wk = (const float*)d_in[3];
  const float* bk = (const float*)d_in[4];
  const float* Wv = (const float*)d_in[5];
  const float* bv = (const float*)d_in[6];
  const float* Wo = (const float*)d_in[7];
  const float* bo = (const float*)d_in[8];
  float* out = (float*)d_out;

  char* ws = (char*)d_ws;
  constexpr size_t QKV_OFF  = 0;                       // 25165824
  constexpr size_t VT_OFF   = 25165824;                // 4194304
  constexpr size_t ATTN_OFF = VT_OFF + 4194304;        // 16777216
  constexpr size_t WT_OFF   = ATTN_OFF + 16777216;     // 12582912
  constexpr size_t BIAS_OFF = WT_OFF + 12582912;
  _Float16* QKV  = (_Float16*)(ws + QKV_OFF);
  _Float16* Vt   = (_Float16*)(ws + VT_OFF);
  _Float16* attn = (_Float16*)(ws + ATTN_OFF);
  _Float16* WT   = (_Float16*)(ws + WT_OFF);
  float*    bqkv = (float*)(ws + BIAS_OFF);
  _Float16* xb = (_Float16*)d_out;  // dead before final GEMM writes d_out

  cast_f32_f16<<<8192, 256, 0, stream>>>(x, xb, (2 * 2048 * 2048) / 4);
  wqkvtrans_kernel<<<dim3(48, 32), 256, 0, stream>>>(Wq, Wk, Wv, WT);
  biaspack_kernel<<<12, 256, 0, stream>>>(bq, bk, bv, bqkv);
  gemm_nt<true><<<dim3(3072 / 128, 4096 / 128), 256, 0, stream>>>(xb, WT, bqkv, QKV, 4096, 3072, 2048);
  wtrans_kernel<<<dim3(32, 32), 256, 0, stream>>>(Wo, WT, 2048, 2048, 0, 2048);
  rope_kernel<<<4096, 256, 0, stream>>>(QKV);
  vtrans_kernel<<<dim3(32, 2, 8), 256, 0, stream>>>(QKV, Vt);
  attn_kernel<<<512, 512, 0, stream>>>(QKV, Vt, attn);
  gemm_nt<false><<<dim3(2048 / 128, 4096 / 128), 256, 0, stream>>>(attn, WT, bo, out, 4096, 2048, 2048);
}